// Round 1
// baseline (2685.586 us; speedup 1.0000x reference)
//
#include <hip/hip_runtime.h>
#include <hip/hip_bf16.h>
#include <math.h>

#define D_MODEL 1024
#define D_STATE 16
#define D_INNER 2048
#define DT_RANK 64
#define BATCH   2
#define SEQLEN  2048
#define NPROJ   96   // DT_RANK + 2*D_STATE

__device__ __forceinline__ float silu_f(float x) { return x / (1.f + __expf(-x)); }

// ---------------- generic NT GEMM: C[m,n] = sum_k A[m,k]*B[n,k] ----------------
// 64x64 tile, BK=16, 256 threads, 4x4 per thread. M,N mult of 64, K mult of 16.
template<int RELU>
__global__ __launch_bounds__(256) void gemm_nt_k(
    const float* __restrict__ A, const float* __restrict__ B, float* __restrict__ C,
    int M, int N, int K, int lda, int ldb, int ldc,
    long long sA, long long sB, long long sC)
{
    __shared__ float As[16][68];
    __shared__ float Bs[16][68];
    const int bz = blockIdx.z;
    A += (long long)bz * sA; B += (long long)bz * sB; C += (long long)bz * sC;
    const int m0 = blockIdx.y * 64, n0 = blockIdx.x * 64;
    const int tid = threadIdx.x;
    const int lk = tid & 15, lr = tid >> 4;   // load: k fast (coalesced 16-wide)
    const int tx = tid & 15, ty = tid >> 4;   // compute: 4x4
    float acc[4][4] = {};
    for (int k0 = 0; k0 < K; k0 += 16) {
        #pragma unroll
        for (int q = 0; q < 4; ++q) {
            int i = lr + q * 16;
            As[lk][i] = A[(long long)(m0 + i) * lda + k0 + lk];
            Bs[lk][i] = B[(long long)(n0 + i) * ldb + k0 + lk];
        }
        __syncthreads();
        #pragma unroll
        for (int k = 0; k < 16; ++k) {
            float a[4], b[4];
            #pragma unroll
            for (int j = 0; j < 4; ++j) { a[j] = As[k][ty*4+j]; b[j] = Bs[k][tx*4+j]; }
            #pragma unroll
            for (int i = 0; i < 4; ++i)
                #pragma unroll
                for (int j = 0; j < 4; ++j) acc[i][j] += a[i] * b[j];
        }
        __syncthreads();
    }
    #pragma unroll
    for (int i = 0; i < 4; ++i)
        #pragma unroll
        for (int j = 0; j < 4; ++j) {
            float v = acc[i][j];
            if (RELU) v = fmaxf(v, 0.f);
            C[(long long)(m0 + ty*4 + i) * ldc + n0 + tx*4 + j] = v;
        }
}

// ---------------- Aneg = -exp(A_log) ----------------
__global__ void aneg_k(const float* __restrict__ A_log, float* __restrict__ Aneg) {
    int i = blockIdx.x * 256 + threadIdx.x;
    if (i < D_INNER * D_STATE) Aneg[i] = -expf(A_log[i]);
}

// ---------------- depthwise causal conv(4) + bias + SiLU ----------------
__global__ void conv_silu_k(const float* __restrict__ xz, const float* __restrict__ cw,
                            const float* __restrict__ cb, float* __restrict__ u)
{
    int idx = blockIdx.x * 256 + threadIdx.x;     // (b,d,l): b*2^22 + d*2^11 + l
    int l = idx & (SEQLEN - 1);
    int d = (idx >> 11) & (D_INNER - 1);
    int b = idx >> 22;
    const float* xi = xz + ((long long)b * 2 * D_INNER + d) * SEQLEN;
    float acc = cb[d];
    #pragma unroll
    for (int k = 0; k < 4; ++k) {
        int t = l + k - 3;
        if (t >= 0) acc += xi[t] * cw[d * 4 + k];
    }
    u[idx] = silu_f(acc);
}

// ---------------- x_dbl[b,l,e] = sum_d u[b,d,l] * W_x[e,d]  (k-split + atomics) --
__global__ __launch_bounds__(256) void xdbl_k(const float* __restrict__ u,
    const float* __restrict__ Wx, float* __restrict__ xdbl)
{
    __shared__ float Us[32][65];
    __shared__ float Ws[32][96];
    const int b = blockIdx.z;
    const int l0 = blockIdx.x * 64;
    const int k0base = blockIdx.y * 512;
    const int tid = threadIdx.x;
    const int lx = tid & 63, eg = tid >> 6;      // 4 e-groups of 24
    float acc[24] = {};
    for (int kc = 0; kc < 16; ++kc) {
        int k0 = k0base + kc * 32;
        #pragma unroll
        for (int q = 0; q < 8; ++q) {            // 2048 elems of u tile
            int f = tid + q * 256;
            int kk = f >> 6, l = f & 63;
            Us[kk][l] = u[((long long)b * D_INNER + k0 + kk) * SEQLEN + l0 + l];
        }
        #pragma unroll
        for (int q = 0; q < 12; ++q) {           // 3072 elems of W_x tile
            int f = tid + q * 256;
            int kk = f & 31, e = f >> 5;
            Ws[kk][e] = Wx[(long long)e * D_INNER + k0 + kk];
        }
        __syncthreads();
        #pragma unroll
        for (int kk = 0; kk < 32; ++kk) {
            float a = Us[kk][lx];
            #pragma unroll
            for (int j = 0; j < 24; ++j) acc[j] += a * Ws[kk][eg * 24 + j];
        }
        __syncthreads();
    }
    #pragma unroll
    for (int j = 0; j < 24; ++j)
        atomicAdd(&xdbl[((long long)b * SEQLEN + l0 + lx) * NPROJ + eg * 24 + j], acc[j]);
}

// ---------------- delta = softplus(dt + b_dt) in place ----------------
__global__ void softplus_k(float* __restrict__ dtb, const float* __restrict__ b_dt) {
    int idx = blockIdx.x * 256 + threadIdx.x;
    int d = (idx >> 11) & (D_INNER - 1);
    float v = dtb[idx] + b_dt[d];
    dtb[idx] = fmaxf(v, 0.f) + log1pf(expf(-fabsf(v)));
}

// ---------------- selective scan: 16 lanes per (b,d) chain ----------------
__global__ __launch_bounds__(64) void scan_k(const float* __restrict__ delta,
    const float* __restrict__ u, const float* __restrict__ xdbl,
    const float* __restrict__ Aneg, float* __restrict__ y)
{
    const int g = blockIdx.x * 4 + (threadIdx.x >> 4);   // chain id = b*D_INNER+d
    const int n = threadIdx.x & 15;
    const int b = g >> 11, d = g & (D_INNER - 1);
    const float a = Aneg[d * D_STATE + n];
    const float* dl = delta + (long long)g * SEQLEN;
    const float* ul = u + (long long)g * SEQLEN;
    const float* xb = xdbl + (long long)b * SEQLEN * NPROJ;
    float* yl = y + (long long)g * SEQLEN;
    float s = 0.f;
    for (int t = 0; t < SEQLEN; ++t) {
        float dt = dl[t], ut = ul[t];
        float Bt = xb[t * NPROJ + DT_RANK + n];
        float Ct = xb[t * NPROJ + DT_RANK + D_STATE + n];
        s = __expf(dt * a) * s + (dt * ut) * Bt;
        float p = s * Ct;
        p += __shfl_xor(p, 8, 16);
        p += __shfl_xor(p, 4, 16);
        p += __shfl_xor(p, 2, 16);
        p += __shfl_xor(p, 1, 16);
        if (n == 0) yl[t] = p;
    }
}

// ---------------- S[b,l] = sum_d Dp[d]*u[b,d,l]  (d-split + atomics) ----------
__global__ void ssum_k(const float* __restrict__ u, const float* __restrict__ Dp,
                       float* __restrict__ S)
{
    int li = blockIdx.x * 256 + threadIdx.x;   // over B*L
    int c = blockIdx.y;
    int b = li >> 11, l = li & (SEQLEN - 1);
    const float* up = u + (long long)b * D_INNER * SEQLEN + l;
    float acc = 0.f;
    for (int d = c * 256; d < c * 256 + 256; ++d)
        acc += Dp[d] * up[(long long)d * SEQLEN];
    atomicAdd(&S[li], acc);
}

// ---------------- y=(y+Dp*u)*silu(z), transposed into ycat[...,:2048] ---------
__global__ __launch_bounds__(256) void ytrans_k(const float* __restrict__ ysc,
    const float* __restrict__ u, const float* __restrict__ xz,
    const float* __restrict__ Dp, float* __restrict__ ycat)
{
    __shared__ float tile[32][33];
    const int b = blockIdx.z;
    const int d0 = blockIdx.y * 32, l0 = blockIdx.x * 32;
    const int lx = threadIdx.x, dy = threadIdx.y;   // (32,8)
    #pragma unroll
    for (int j = 0; j < 4; ++j) {
        int d = d0 + dy + j * 8;
        long long i  = ((long long)b * D_INNER + d) * SEQLEN + l0 + lx;
        long long iz = ((long long)b * 2 * D_INNER + D_INNER + d) * SEQLEN + l0 + lx;
        tile[dy + j * 8][lx] = (ysc[i] + Dp[d] * u[i]) * silu_f(xz[iz]);
    }
    __syncthreads();
    #pragma unroll
    for (int j = 0; j < 4; ++j) {
        int l = l0 + dy + j * 8;
        ycat[((long long)b * SEQLEN + l) * (2 * D_INNER) + d0 + lx] = tile[lx][dy + j * 8];
    }
}

// ---------------- y_t[b,l,d] = sum_n Cm[b,n,l]*Aneg[d,n] + S[b,l] -> ycat[...,2048:]
__global__ __launch_bounds__(256) void yt_k(const float* __restrict__ xdbl,
    const float* __restrict__ Aneg, const float* __restrict__ S, float* __restrict__ ycat)
{
    __shared__ float Cs[16][33];
    __shared__ float An[16][64];
    __shared__ float Sv[32];
    const int b = blockIdx.z;
    const int d0 = blockIdx.y * 64, l0 = blockIdx.x * 32;
    const int tid = threadIdx.x;
    for (int f = tid; f < 512; f += 256) {
        int n = f & 15, l = f >> 4;
        Cs[n][l] = xdbl[((long long)b * SEQLEN + l0 + l) * NPROJ + DT_RANK + D_STATE + n];
    }
    for (int f = tid; f < 1024; f += 256) {
        int n = f & 15, d = f >> 4;
        An[n][d] = Aneg[(d0 + d) * D_STATE + n];
    }
    if (tid < 32) Sv[tid] = S[b * SEQLEN + l0 + tid];
    __syncthreads();
    const int dx = tid & 63, lg = tid >> 6;
    #pragma unroll
    for (int j = 0; j < 8; ++j) {
        int l = lg * 8 + j;
        float acc = Sv[l];
        #pragma unroll
        for (int n = 0; n < 16; ++n) acc += Cs[n][l] * An[n][dx];
        ycat[((long long)b * SEQLEN + l0 + l) * (2 * D_INNER) + D_INNER + d0 + dx] = acc;
    }
}

extern "C" void kernel_launch(void* const* d_in, const int* in_sizes, int n_in,
                              void* d_out, int out_size, void* d_ws, size_t ws_size,
                              hipStream_t stream)
{
    const float* x      = (const float*)d_in[0];
    const float* W_in   = (const float*)d_in[1];
    const float* conv_w = (const float*)d_in[2];
    const float* conv_b = (const float*)d_in[3];
    const float* W_x    = (const float*)d_in[4];
    const float* W_dt   = (const float*)d_in[5];
    const float* b_dt   = (const float*)d_in[6];
    const float* A_log  = (const float*)d_in[7];
    const float* Dp     = (const float*)d_in[8];
    const float* W_out1 = (const float*)d_in[9];
    const float* W_out2 = (const float*)d_in[10];
    float* out = (float*)d_out;
    float* ws  = (float*)d_ws;

    // workspace layout (floats); total ~236.6 MB. h reuses dead xz region.
    float* xz   = ws;                    // B*4096*L          = 16777216
    float* u    = xz   + 16777216;       // B*2048*L          =  8388608
    float* xdbl = u    + 8388608;        // B*L*96            =   393216
    float* dtb  = xdbl + 393216;         // B*2048*L (->delta)=  8388608
    float* ysc  = dtb  + 8388608;        // B*2048*L          =  8388608
    float* Aneg = ysc  + 8388608;        // 2048*16           =    32768
    float* S    = Aneg + 32768;          // B*L               =     4096
    float* ycat = S    + 4096;           // B*L*4096          = 16777216
    float* h    = xz;                    // B*L*2048 (reuse)

    hipMemsetAsync(xdbl, 0, 393216 * sizeof(float), stream);
    hipMemsetAsync(S, 0, 4096 * sizeof(float), stream);
    aneg_k<<<128, 256, 0, stream>>>(A_log, Aneg);

    // xz[b,e,l] = sum_d W_in[e,d] * x[b,l,d]
    gemm_nt_k<0><<<dim3(SEQLEN/64, 4096/64, BATCH), 256, 0, stream>>>(
        W_in, x, xz, 4096, SEQLEN, D_MODEL, D_MODEL, D_MODEL, SEQLEN,
        0LL, (long long)SEQLEN * D_MODEL, (long long)4096 * SEQLEN);

    conv_silu_k<<<(BATCH * D_INNER * SEQLEN) / 256, 256, 0, stream>>>(xz, conv_w, conv_b, u);

    xdbl_k<<<dim3(SEQLEN/64, 4, BATCH), 256, 0, stream>>>(u, W_x, xdbl);

    // dt[b,d,l] = sum_r W_dt[d,r] * x_dbl[b,l,r]
    gemm_nt_k<0><<<dim3(SEQLEN/64, D_INNER/64, BATCH), 256, 0, stream>>>(
        W_dt, xdbl, dtb, D_INNER, SEQLEN, DT_RANK, DT_RANK, NPROJ, SEQLEN,
        0LL, (long long)SEQLEN * NPROJ, (long long)D_INNER * SEQLEN);

    softplus_k<<<(BATCH * D_INNER * SEQLEN) / 256, 256, 0, stream>>>(dtb, b_dt);

    scan_k<<<(BATCH * D_INNER) / 4, 64, 0, stream>>>(dtb, u, xdbl, Aneg, ysc);

    ssum_k<<<dim3((BATCH * SEQLEN) / 256, 8), 256, 0, stream>>>(u, Dp, S);

    ytrans_k<<<dim3(SEQLEN/32, D_INNER/32, BATCH), dim3(32, 8), 0, stream>>>(ysc, u, xz, Dp, ycat);

    yt_k<<<dim3(SEQLEN/32, D_INNER/64, BATCH), 256, 0, stream>>>(xdbl, Aneg, S, ycat);

    // h = relu(ycat @ W_out1^T), flat M = B*L
    gemm_nt_k<1><<<dim3(D_INNER/64, (BATCH*SEQLEN)/64, 1), 256, 0, stream>>>(
        ycat, W_out1, h, BATCH * SEQLEN, D_INNER, 2 * D_INNER,
        2 * D_INNER, 2 * D_INNER, D_INNER, 0LL, 0LL, 0LL);

    // out = h @ W_out2^T
    gemm_nt_k<0><<<dim3(D_MODEL/64, (BATCH*SEQLEN)/64, 1), 256, 0, stream>>>(
        h, W_out2, out, BATCH * SEQLEN, D_MODEL, D_INNER,
        D_INNER, D_INNER, D_MODEL, 0LL, 0LL, 0LL);
}

// Round 6
// 1248.159 us; speedup vs baseline: 2.1516x; 2.1516x over previous
//
#include <hip/hip_runtime.h>
#include <hip/hip_bf16.h>
#include <math.h>

#define D_MODEL 1024
#define D_STATE 16
#define D_INNER 2048
#define DT_RANK 64
#define BATCH   2
#define SEQLEN  2048
#define NPROJ   96   // DT_RANK + 2*D_STATE

typedef __attribute__((ext_vector_type(8))) __bf16 bf16x8;
typedef __attribute__((ext_vector_type(4))) float f32x4;

__device__ __forceinline__ float silu_f(float x) { return x / (1.f + __expf(-x)); }

__device__ __forceinline__ void gload_lds16(const void* g, void* l) {
    __builtin_amdgcn_global_load_lds((const __attribute__((address_space(1))) void*)g,
                                     (__attribute__((address_space(3))) void*)l, 16, 0, 0);
}

// ---------------- bf16 MFMA NT GEMM: C[m,n] = sum_k A[m,k]*B[n,k] -------------
// BM=BN=128, BK=32, 256 threads = 4 waves (2x2), 64x64 per wave.
// One mfma_16x16x32 consumes the full BK=32 (lane k-offset = (lane>>4)*8).
// M,N mult of 128, K mult of 32. A un-batched, B/C batched via strides.
template<int RELU, int OUT_BF16>
__global__ __launch_bounds__(256) void gemm_bf16_k(
    const __bf16* __restrict__ A, const __bf16* __restrict__ B, void* __restrict__ Cv,
    int K, int lda, int ldb, int ldc, long long sB, long long sC)
{
    __shared__ alignas(16) __bf16 As[128 * 32];
    __shared__ alignas(16) __bf16 Bs[128 * 32];
    const int bz = blockIdx.z;
    B += (long long)bz * sB;
    const int m0 = blockIdx.y * 128, n0 = blockIdx.x * 128;
    const int tid = threadIdx.x;
    const int lane = tid & 63;
    const int wv = tid >> 6;
    const int wr = wv >> 1, wc = wv & 1;

    f32x4 acc[4][4];
    #pragma unroll
    for (int i = 0; i < 4; ++i)
        #pragma unroll
        for (int j = 0; j < 4; ++j) acc[i][j] = (f32x4){0.f, 0.f, 0.f, 0.f};

    const int ko = (lane >> 4) * 8;           // k-offset within BK=32
    const int fr = lane & 15;                 // fragment row/col within 16

    for (int k0 = 0; k0 < K; k0 += 32) {
        #pragma unroll
        for (int q = 0; q < 2; ++q) {
            int f = tid + q * 256;
            int row = f >> 2, c16 = f & 3;    // 4 x 16B per 32-elem row
            gload_lds16(A + (long long)(m0 + row) * lda + k0 + c16 * 8, As + f * 8);
            gload_lds16(B + (long long)(n0 + row) * ldb + k0 + c16 * 8, Bs + f * 8);
        }
        __syncthreads();
        bf16x8 a[4], b[4];
        #pragma unroll
        for (int i = 0; i < 4; ++i) {
            a[i] = *(const bf16x8*)(As + (wr * 64 + i * 16 + fr) * 32 + ko);
            b[i] = *(const bf16x8*)(Bs + (wc * 64 + i * 16 + fr) * 32 + ko);
        }
        #pragma unroll
        for (int i = 0; i < 4; ++i)
            #pragma unroll
            for (int j = 0; j < 4; ++j)
                acc[i][j] = __builtin_amdgcn_mfma_f32_16x16x32_bf16(a[i], b[j], acc[i][j], 0, 0, 0);
        __syncthreads();
    }

    #pragma unroll
    for (int i = 0; i < 4; ++i) {
        const int row = m0 + wr * 64 + i * 16 + (lane >> 4) * 4;
        #pragma unroll
        for (int j = 0; j < 4; ++j) {
            const int col = n0 + wc * 64 + j * 16 + fr;
            #pragma unroll
            for (int r = 0; r < 4; ++r) {
                float v = acc[i][j][r];
                if (RELU) v = fmaxf(v, 0.f);
                if (OUT_BF16)
                    ((__bf16*)Cv)[(long long)bz * sC + (long long)(row + r) * ldc + col] = (__bf16)v;
                else
                    ((float*)Cv)[(long long)bz * sC + (long long)(row + r) * ldc + col] = v;
            }
        }
    }
}

// ---------------- f32 -> bf16 pack (8 per thread) ----------------
__global__ void cvt_bf16_k(const float* __restrict__ in, __bf16* __restrict__ out, int n8) {
    int i = blockIdx.x * 256 + threadIdx.x;
    if (i >= n8) return;
    const f32x4* p = (const f32x4*)in + (long long)i * 2;
    f32x4 v0 = p[0], v1 = p[1];
    bf16x8 o;
    o[0] = (__bf16)v0[0]; o[1] = (__bf16)v0[1]; o[2] = (__bf16)v0[2]; o[3] = (__bf16)v0[3];
    o[4] = (__bf16)v1[0]; o[5] = (__bf16)v1[1]; o[6] = (__bf16)v1[2]; o[7] = (__bf16)v1[3];
    ((bf16x8*)out)[i] = o;
}

// ---------------- generic fp32 NT GEMM (kept for small dt GEMM) ----------------
template<int RELU>
__global__ __launch_bounds__(256) void gemm_nt_k(
    const float* __restrict__ A, const float* __restrict__ B, float* __restrict__ C,
    int M, int N, int K, int lda, int ldb, int ldc,
    long long sA, long long sB, long long sC)
{
    __shared__ float As[16][68];
    __shared__ float Bs[16][68];
    const int bz = blockIdx.z;
    A += (long long)bz * sA; B += (long long)bz * sB; C += (long long)bz * sC;
    const int m0 = blockIdx.y * 64, n0 = blockIdx.x * 64;
    const int tid = threadIdx.x;
    const int lk = tid & 15, lr = tid >> 4;
    const int tx = tid & 15, ty = tid >> 4;
    float acc[4][4] = {};
    for (int k0 = 0; k0 < K; k0 += 16) {
        #pragma unroll
        for (int q = 0; q < 4; ++q) {
            int i = lr + q * 16;
            As[lk][i] = A[(long long)(m0 + i) * lda + k0 + lk];
            Bs[lk][i] = B[(long long)(n0 + i) * ldb + k0 + lk];
        }
        __syncthreads();
        #pragma unroll
        for (int k = 0; k < 16; ++k) {
            float a[4], b[4];
            #pragma unroll
            for (int j = 0; j < 4; ++j) { a[j] = As[k][ty*4+j]; b[j] = Bs[k][tx*4+j]; }
            #pragma unroll
            for (int i = 0; i < 4; ++i)
                #pragma unroll
                for (int j = 0; j < 4; ++j) acc[i][j] += a[i] * b[j];
        }
        __syncthreads();
    }
    #pragma unroll
    for (int i = 0; i < 4; ++i)
        #pragma unroll
        for (int j = 0; j < 4; ++j) {
            float v = acc[i][j];
            if (RELU) v = fmaxf(v, 0.f);
            C[(long long)(m0 + ty*4 + i) * ldc + n0 + tx*4 + j] = v;
        }
}

// ---------------- Aneg = -exp(A_log) ----------------
__global__ void aneg_k(const float* __restrict__ A_log, float* __restrict__ Aneg) {
    int i = blockIdx.x * 256 + threadIdx.x;
    if (i < D_INNER * D_STATE) Aneg[i] = -expf(A_log[i]);
}

// ---------------- depthwise causal conv(4) + bias + SiLU ----------------
__global__ void conv_silu_k(const float* __restrict__ xz, const float* __restrict__ cw,
                            const float* __restrict__ cb, float* __restrict__ u)
{
    int idx = blockIdx.x * 256 + threadIdx.x;
    int l = idx & (SEQLEN - 1);
    int d = (idx >> 11) & (D_INNER - 1);
    int b = idx >> 22;
    const float* xi = xz + ((long long)b * 2 * D_INNER + d) * SEQLEN;
    float acc = cb[d];
    #pragma unroll
    for (int k = 0; k < 4; ++k) {
        int t = l + k - 3;
        if (t >= 0) acc += xi[t] * cw[d * 4 + k];
    }
    u[idx] = silu_f(acc);
}

// ---------------- x_dbl[b,l,e] = sum_d u[b,d,l] * W_x[e,d] ----------------
__global__ __launch_bounds__(256) void xdbl_k(const float* __restrict__ u,
    const float* __restrict__ Wx, float* __restrict__ xdbl)
{
    __shared__ float Us[32][65];
    __shared__ float Ws[32][96];
    const int b = blockIdx.z;
    const int l0 = blockIdx.x * 64;
    const int k0base = blockIdx.y * 512;
    const int tid = threadIdx.x;
    const int lx = tid & 63, eg = tid >> 6;
    float acc[24] = {};
    for (int kc = 0; kc < 16; ++kc) {
        int k0 = k0base + kc * 32;
        #pragma unroll
        for (int q = 0; q < 8; ++q) {
            int f = tid + q * 256;
            int kk = f >> 6, l = f & 63;
            Us[kk][l] = u[((long long)b * D_INNER + k0 + kk) * SEQLEN + l0 + l];
        }
        #pragma unroll
        for (int q = 0; q < 12; ++q) {
            int f = tid + q * 256;
            int kk = f & 31, e = f >> 5;
            Ws[kk][e] = Wx[(long long)e * D_INNER + k0 + kk];
        }
        __syncthreads();
        #pragma unroll
        for (int kk = 0; kk < 32; ++kk) {
            float a = Us[kk][lx];
            #pragma unroll
            for (int j = 0; j < 24; ++j) acc[j] += a * Ws[kk][eg * 24 + j];
        }
        __syncthreads();
    }
    #pragma unroll
    for (int j = 0; j < 24; ++j)
        atomicAdd(&xdbl[((long long)b * SEQLEN + l0 + lx) * NPROJ + eg * 24 + j], acc[j]);
}

// ---------------- delta = softplus(dt + b_dt) in place ----------------
__global__ void softplus_k(float* __restrict__ dtb, const float* __restrict__ b_dt) {
    int idx = blockIdx.x * 256 + threadIdx.x;
    int d = (idx >> 11) & (D_INNER - 1);
    float v = dtb[idx] + b_dt[d];
    dtb[idx] = fmaxf(v, 0.f) + log1pf(expf(-fabsf(v)));
}

// ---------------- selective scan: 16 lanes per (b,d) chain ----------------
__global__ __launch_bounds__(64) void scan_k(const float* __restrict__ delta,
    const float* __restrict__ u, const float* __restrict__ xdbl,
    const float* __restrict__ Aneg, float* __restrict__ y)
{
    const int g = blockIdx.x * 4 + (threadIdx.x >> 4);
    const int n = threadIdx.x & 15;
    const int b = g >> 11, d = g & (D_INNER - 1);
    const float a = Aneg[d * D_STATE + n];
    const float* dl = delta + (long long)g * SEQLEN;
    const float* ul = u + (long long)g * SEQLEN;
    const float* xb = xdbl + (long long)b * SEQLEN * NPROJ;
    float* yl = y + (long long)g * SEQLEN;
    float s = 0.f;
    for (int t = 0; t < SEQLEN; ++t) {
        float dt = dl[t], ut = ul[t];
        float Bt = xb[t * NPROJ + DT_RANK + n];
        float Ct = xb[t * NPROJ + DT_RANK + D_STATE + n];
        s = __expf(dt * a) * s + (dt * ut) * Bt;
        float p = s * Ct;
        p += __shfl_xor(p, 8, 16);
        p += __shfl_xor(p, 4, 16);
        p += __shfl_xor(p, 2, 16);
        p += __shfl_xor(p, 1, 16);
        if (n == 0) yl[t] = p;
    }
}

// ---------------- S[b,l] = sum_d Dp[d]*u[b,d,l] ----------------
__global__ void ssum_k(const float* __restrict__ u, const float* __restrict__ Dp,
                       float* __restrict__ S)
{
    int li = blockIdx.x * 256 + threadIdx.x;
    int c = blockIdx.y;
    int b = li >> 11, l = li & (SEQLEN - 1);
    const float* up = u + (long long)b * D_INNER * SEQLEN + l;
    float acc = 0.f;
    for (int d = c * 256; d < c * 256 + 256; ++d)
        acc += Dp[d] * up[(long long)d * SEQLEN];
    atomicAdd(&S[li], acc);
}

// ---------------- y=(y+Dp*u)*silu(z), transposed into ycat16[...,:2048] -------
__global__ __launch_bounds__(256) void ytrans_k(const float* __restrict__ ysc,
    const float* __restrict__ u, const float* __restrict__ xz,
    const float* __restrict__ Dp, __bf16* __restrict__ ycat)
{
    __shared__ float tile[32][33];
    const int b = blockIdx.z;
    const int d0 = blockIdx.y * 32, l0 = blockIdx.x * 32;
    const int lx = threadIdx.x, dy = threadIdx.y;
    #pragma unroll
    for (int j = 0; j < 4; ++j) {
        int d = d0 + dy + j * 8;
        long long i  = ((long long)b * D_INNER + d) * SEQLEN + l0 + lx;
        long long iz = ((long long)b * 2 * D_INNER + D_INNER + d) * SEQLEN + l0 + lx;
        tile[dy + j * 8][lx] = (ysc[i] + Dp[d] * u[i]) * silu_f(xz[iz]);
    }
    __syncthreads();
    #pragma unroll
    for (int j = 0; j < 4; ++j) {
        int l = l0 + dy + j * 8;
        ycat[((long long)b * SEQLEN + l) * (2 * D_INNER) + d0 + lx] = (__bf16)tile[lx][dy + j * 8];
    }
}

// ---------------- y_t -> ycat16[...,2048:] ----------------
__global__ __launch_bounds__(256) void yt_k(const float* __restrict__ xdbl,
    const float* __restrict__ Aneg, const float* __restrict__ S, __bf16* __restrict__ ycat)
{
    __shared__ float Cs[16][33];
    __shared__ float An[16][64];
    __shared__ float Sv[32];
    const int b = blockIdx.z;
    const int d0 = blockIdx.y * 64, l0 = blockIdx.x * 32;
    const int tid = threadIdx.x;
    for (int f = tid; f < 512; f += 256) {
        int n = f & 15, l = f >> 4;
        Cs[n][l] = xdbl[((long long)b * SEQLEN + l0 + l) * NPROJ + DT_RANK + D_STATE + n];
    }
    for (int f = tid; f < 1024; f += 256) {
        int n = f & 15, d = f >> 4;
        An[n][d] = Aneg[(d0 + d) * D_STATE + n];
    }
    if (tid < 32) Sv[tid] = S[b * SEQLEN + l0 + tid];
    __syncthreads();
    const int dx = tid & 63, lg = tid >> 6;
    #pragma unroll
    for (int j = 0; j < 8; ++j) {
        int l = lg * 8 + j;
        float acc = Sv[l];
        #pragma unroll
        for (int n = 0; n < 16; ++n) acc += Cs[n][l] * An[n][dx];
        ycat[((long long)b * SEQLEN + l0 + l) * (2 * D_INNER) + D_INNER + d0 + dx] = (__bf16)acc;
    }
}

extern "C" void kernel_launch(void* const* d_in, const int* in_sizes, int n_in,
                              void* d_out, int out_size, void* d_ws, size_t ws_size,
                              hipStream_t stream)
{
    const float* x      = (const float*)d_in[0];
    const float* W_in   = (const float*)d_in[1];
    const float* conv_w = (const float*)d_in[2];
    const float* conv_b = (const float*)d_in[3];
    const float* W_x    = (const float*)d_in[4];
    const float* W_dt   = (const float*)d_in[5];
    const float* b_dt   = (const float*)d_in[6];
    const float* A_log  = (const float*)d_in[7];
    const float* Dp     = (const float*)d_in[8];
    const float* W_out1 = (const float*)d_in[9];
    const float* W_out2 = (const float*)d_in[10];
    float* out = (float*)d_out;
    float* ws  = (float*)d_ws;

    // fp32 region (169.5 MB)
    float* xz   = ws;                    // 16777216
    float* u    = xz   + 16777216;       //  8388608
    float* xdbl = u    + 8388608;        //   393216
    float* dtb  = xdbl + 393216;         //  8388608 (delta)
    float* ysc  = dtb  + 8388608;        //  8388608
    float* Aneg = ysc  + 8388608;        //    32768
    float* S    = Aneg + 32768;          //     4096
    // bf16 tail (50.4 MB)
    __bf16* ycat16 = (__bf16*)(S + 4096);          // 16777216 el
    __bf16* h16    = ycat16 + 16777216;            //  8388608 el
    // overlays (regions dead at time of use)
    __bf16* W_in16  = (__bf16*)u;                  // 4194304 el (before conv writes u)
    __bf16* xb16    = W_in16 + 4194304;            // 4194304 el
    __bf16* Wout116 = (__bf16*)dtb;                // 8388608 el (after scan reads dtb)
    __bf16* Wout216 = Wout116 + 8388608;           // 2097152 el

    hipMemsetAsync(xdbl, 0, 393216 * sizeof(float), stream);
    hipMemsetAsync(S, 0, 4096 * sizeof(float), stream);
    aneg_k<<<128, 256, 0, stream>>>(A_log, Aneg);

    // bf16 conversions for input GEMM
    cvt_bf16_k<<<2048, 256, 0, stream>>>(W_in, W_in16, 524288);
    cvt_bf16_k<<<2048, 256, 0, stream>>>(x, xb16, 524288);

    // xz[b,e,l] = sum_d W_in[e,d] * x[b,l,d]   (M=4096, N=2048, K=1024)
    gemm_bf16_k<0, 0><<<dim3(16, 32, BATCH), 256, 0, stream>>>(
        W_in16, xb16, xz, D_MODEL, D_MODEL, D_MODEL, SEQLEN,
        (long long)SEQLEN * D_MODEL, (long long)4096 * SEQLEN);

    conv_silu_k<<<(BATCH * D_INNER * SEQLEN) / 256, 256, 0, stream>>>(xz, conv_w, conv_b, u);

    xdbl_k<<<dim3(SEQLEN / 64, 4, BATCH), 256, 0, stream>>>(u, W_x, xdbl);

    // dt[b,d,l] = sum_r W_dt[d,r] * x_dbl[b,l,r]   (small K=64, fp32)
    gemm_nt_k<0><<<dim3(SEQLEN / 64, D_INNER / 64, BATCH), 256, 0, stream>>>(
        W_dt, xdbl, dtb, D_INNER, SEQLEN, DT_RANK, DT_RANK, NPROJ, SEQLEN,
        0LL, (long long)SEQLEN * NPROJ, (long long)D_INNER * SEQLEN);

    softplus_k<<<(BATCH * D_INNER * SEQLEN) / 256, 256, 0, stream>>>(dtb, b_dt);

    scan_k<<<(BATCH * D_INNER) / 4, 64, 0, stream>>>(dtb, u, xdbl, Aneg, ysc);

    // weight conversions for output GEMMs (dtb region dead now)
    cvt_bf16_k<<<4096, 256, 0, stream>>>(W_out1, Wout116, 1048576);
    cvt_bf16_k<<<1024, 256, 0, stream>>>(W_out2, Wout216, 262144);

    ssum_k<<<dim3((BATCH * SEQLEN) / 256, 8), 256, 0, stream>>>(u, Dp, S);

    ytrans_k<<<dim3(SEQLEN / 32, D_INNER / 32, BATCH), dim3(32, 8), 0, stream>>>(ysc, u, xz, Dp, ycat16);

    yt_k<<<dim3(SEQLEN / 32, D_INNER / 64, BATCH), 256, 0, stream>>>(xdbl, Aneg, S, ycat16);

    // h = relu(ycat @ W_out1^T) -> bf16   (M=4096, N=2048, K=4096)
    gemm_bf16_k<1, 1><<<dim3(16, 32, 1), 256, 0, stream>>>(
        ycat16, Wout116, h16, 2 * D_INNER, 2 * D_INNER, 2 * D_INNER, D_INNER, 0LL, 0LL);

    // out = h @ W_out2^T   (M=4096, N=1024, K=2048)
    gemm_bf16_k<0, 0><<<dim3(8, 32, 1), 256, 0, stream>>>(
        h16, Wout216, out, D_INNER, D_INNER, D_INNER, D_MODEL, 0LL, 0LL);
}

// Round 7
// 739.669 us; speedup vs baseline: 3.6308x; 1.6875x over previous
//
#include <hip/hip_runtime.h>
#include <hip/hip_bf16.h>
#include <math.h>

#define D_MODEL 1024
#define D_STATE 16
#define D_INNER 2048
#define DT_RANK 64
#define BATCH   2
#define SEQLEN  2048
#define NPROJ   96   // DT_RANK + 2*D_STATE

typedef __attribute__((ext_vector_type(8))) __bf16 bf16x8;
typedef __attribute__((ext_vector_type(4))) float f32x4;

__device__ __forceinline__ float silu_f(float x) { return x / (1.f + __expf(-x)); }

__device__ __forceinline__ void gload_lds16(const void* g, void* l) {
    __builtin_amdgcn_global_load_lds((const __attribute__((address_space(1))) void*)g,
                                     (__attribute__((address_space(3))) void*)l, 16, 0, 0);
}

// ---------------- bf16 MFMA NT GEMM: C[m,n] = sum_k A[m,k]*B[n,k] -------------
// BM=BN=128, BK=32, 256 threads = 4 waves (2x2), 64x64 per wave.
// One mfma_16x16x32 consumes the full BK=32 (lane k-offset = (lane>>4)*8).
// M,N mult of 128, K mult of 32. A un-batched, B/C batched via strides.
template<int RELU, int OUT_BF16>
__global__ __launch_bounds__(256) void gemm_bf16_k(
    const __bf16* __restrict__ A, const __bf16* __restrict__ B, void* __restrict__ Cv,
    int K, int lda, int ldb, int ldc, long long sB, long long sC)
{
    __shared__ alignas(16) __bf16 As[128 * 32];
    __shared__ alignas(16) __bf16 Bs[128 * 32];
    const int bz = blockIdx.z;
    B += (long long)bz * sB;
    const int m0 = blockIdx.y * 128, n0 = blockIdx.x * 128;
    const int tid = threadIdx.x;
    const int lane = tid & 63;
    const int wv = tid >> 6;
    const int wr = wv >> 1, wc = wv & 1;

    f32x4 acc[4][4];
    #pragma unroll
    for (int i = 0; i < 4; ++i)
        #pragma unroll
        for (int j = 0; j < 4; ++j) acc[i][j] = (f32x4){0.f, 0.f, 0.f, 0.f};

    const int ko = (lane >> 4) * 8;           // k-offset within BK=32
    const int fr = lane & 15;                 // fragment row/col within 16

    for (int k0 = 0; k0 < K; k0 += 32) {
        #pragma unroll
        for (int q = 0; q < 2; ++q) {
            int f = tid + q * 256;
            int row = f >> 2, c16 = f & 3;    // 4 x 16B per 32-elem row
            gload_lds16(A + (long long)(m0 + row) * lda + k0 + c16 * 8, As + f * 8);
            gload_lds16(B + (long long)(n0 + row) * ldb + k0 + c16 * 8, Bs + f * 8);
        }
        __syncthreads();
        bf16x8 a[4], b[4];
        #pragma unroll
        for (int i = 0; i < 4; ++i) {
            a[i] = *(const bf16x8*)(As + (wr * 64 + i * 16 + fr) * 32 + ko);
            b[i] = *(const bf16x8*)(Bs + (wc * 64 + i * 16 + fr) * 32 + ko);
        }
        #pragma unroll
        for (int i = 0; i < 4; ++i)
            #pragma unroll
            for (int j = 0; j < 4; ++j)
                acc[i][j] = __builtin_amdgcn_mfma_f32_16x16x32_bf16(a[i], b[j], acc[i][j], 0, 0, 0);
        __syncthreads();
    }

    #pragma unroll
    for (int i = 0; i < 4; ++i) {
        const int row = m0 + wr * 64 + i * 16 + (lane >> 4) * 4;
        #pragma unroll
        for (int j = 0; j < 4; ++j) {
            const int col = n0 + wc * 64 + j * 16 + fr;
            #pragma unroll
            for (int r = 0; r < 4; ++r) {
                float v = acc[i][j][r];
                if (RELU) v = fmaxf(v, 0.f);
                if (OUT_BF16)
                    ((__bf16*)Cv)[(long long)bz * sC + (long long)(row + r) * ldc + col] = (__bf16)v;
                else
                    ((float*)Cv)[(long long)bz * sC + (long long)(row + r) * ldc + col] = v;
            }
        }
    }
}

// ---------------- f32 -> bf16 pack (8 per thread) ----------------
__global__ void cvt_bf16_k(const float* __restrict__ in, __bf16* __restrict__ out, int n8) {
    int i = blockIdx.x * 256 + threadIdx.x;
    if (i >= n8) return;
    const f32x4* p = (const f32x4*)in + (long long)i * 2;
    f32x4 v0 = p[0], v1 = p[1];
    bf16x8 o;
    o[0] = (__bf16)v0[0]; o[1] = (__bf16)v0[1]; o[2] = (__bf16)v0[2]; o[3] = (__bf16)v0[3];
    o[4] = (__bf16)v1[0]; o[5] = (__bf16)v1[1]; o[6] = (__bf16)v1[2]; o[7] = (__bf16)v1[3];
    ((bf16x8*)out)[i] = o;
}

// ---------------- generic fp32 NT GEMM (kept for small dt GEMM) ----------------
template<int RELU>
__global__ __launch_bounds__(256) void gemm_nt_k(
    const float* __restrict__ A, const float* __restrict__ B, float* __restrict__ C,
    int M, int N, int K, int lda, int ldb, int ldc,
    long long sA, long long sB, long long sC)
{
    __shared__ float As[16][68];
    __shared__ float Bs[16][68];
    const int bz = blockIdx.z;
    A += (long long)bz * sA; B += (long long)bz * sB; C += (long long)bz * sC;
    const int m0 = blockIdx.y * 64, n0 = blockIdx.x * 64;
    const int tid = threadIdx.x;
    const int lk = tid & 15, lr = tid >> 4;
    const int tx = tid & 15, ty = tid >> 4;
    float acc[4][4] = {};
    for (int k0 = 0; k0 < K; k0 += 16) {
        #pragma unroll
        for (int q = 0; q < 4; ++q) {
            int i = lr + q * 16;
            As[lk][i] = A[(long long)(m0 + i) * lda + k0 + lk];
            Bs[lk][i] = B[(long long)(n0 + i) * ldb + k0 + lk];
        }
        __syncthreads();
        #pragma unroll
        for (int k = 0; k < 16; ++k) {
            float a[4], b[4];
            #pragma unroll
            for (int j = 0; j < 4; ++j) { a[j] = As[k][ty*4+j]; b[j] = Bs[k][tx*4+j]; }
            #pragma unroll
            for (int i = 0; i < 4; ++i)
                #pragma unroll
                for (int j = 0; j < 4; ++j) acc[i][j] += a[i] * b[j];
        }
        __syncthreads();
    }
    #pragma unroll
    for (int i = 0; i < 4; ++i)
        #pragma unroll
        for (int j = 0; j < 4; ++j) {
            float v = acc[i][j];
            if (RELU) v = fmaxf(v, 0.f);
            C[(long long)(m0 + ty*4 + i) * ldc + n0 + tx*4 + j] = v;
        }
}

// ---------------- Aneg = -exp(A_log) ----------------
__global__ void aneg_k(const float* __restrict__ A_log, float* __restrict__ Aneg) {
    int i = blockIdx.x * 256 + threadIdx.x;
    if (i < D_INNER * D_STATE) Aneg[i] = -expf(A_log[i]);
}

// ---------------- depthwise causal conv(4) + bias + SiLU ----------------
__global__ void conv_silu_k(const float* __restrict__ xz, const float* __restrict__ cw,
                            const float* __restrict__ cb, float* __restrict__ u)
{
    int idx = blockIdx.x * 256 + threadIdx.x;
    int l = idx & (SEQLEN - 1);
    int d = (idx >> 11) & (D_INNER - 1);
    int b = idx >> 22;
    const float* xi = xz + ((long long)b * 2 * D_INNER + d) * SEQLEN;
    float acc = cb[d];
    #pragma unroll
    for (int k = 0; k < 4; ++k) {
        int t = l + k - 3;
        if (t >= 0) acc += xi[t] * cw[d * 4 + k];
    }
    u[idx] = silu_f(acc);
}

// ---------------- x_dbl[b,l,e] = sum_d u[b,d,l] * W_x[e,d] ----------------
__global__ __launch_bounds__(256) void xdbl_k(const float* __restrict__ u,
    const float* __restrict__ Wx, float* __restrict__ xdbl)
{
    __shared__ float Us[32][65];
    __shared__ float Ws[32][96];
    const int b = blockIdx.z;
    const int l0 = blockIdx.x * 64;
    const int k0base = blockIdx.y * 512;
    const int tid = threadIdx.x;
    const int lx = tid & 63, eg = tid >> 6;
    float acc[24] = {};
    for (int kc = 0; kc < 16; ++kc) {
        int k0 = k0base + kc * 32;
        #pragma unroll
        for (int q = 0; q < 8; ++q) {
            int f = tid + q * 256;
            int kk = f >> 6, l = f & 63;
            Us[kk][l] = u[((long long)b * D_INNER + k0 + kk) * SEQLEN + l0 + l];
        }
        #pragma unroll
        for (int q = 0; q < 12; ++q) {
            int f = tid + q * 256;
            int kk = f & 31, e = f >> 5;
            Ws[kk][e] = Wx[(long long)e * D_INNER + k0 + kk];
        }
        __syncthreads();
        #pragma unroll
        for (int kk = 0; kk < 32; ++kk) {
            float a = Us[kk][lx];
            #pragma unroll
            for (int j = 0; j < 24; ++j) acc[j] += a * Ws[kk][eg * 24 + j];
        }
        __syncthreads();
    }
    #pragma unroll
    for (int j = 0; j < 24; ++j)
        atomicAdd(&xdbl[((long long)b * SEQLEN + l0 + lx) * NPROJ + eg * 24 + j], acc[j]);
}

// ---------------- delta = softplus(dt + b_dt) in place ----------------
__global__ void softplus_k(float* __restrict__ dtb, const float* __restrict__ b_dt) {
    int idx = blockIdx.x * 256 + threadIdx.x;
    int d = (idx >> 11) & (D_INNER - 1);
    float v = dtb[idx] + b_dt[d];
    dtb[idx] = fmaxf(v, 0.f) + log1pf(expf(-fabsf(v)));
}

// ---------------- selective scan: 16 lanes per (b,d) chain, 8-step pipeline ---
// Loads of block t0+8 are issued while block t0 computes from registers; only
// the s-recurrence is serial. All reg arrays fully unrolled (static indices).
__global__ __launch_bounds__(64) void scan_k(const float* __restrict__ delta,
    const float* __restrict__ u, const float* __restrict__ xdbl,
    const float* __restrict__ Aneg, float* __restrict__ y)
{
    const int g = blockIdx.x * 4 + (threadIdx.x >> 4);
    const int n = threadIdx.x & 15;
    const int b = g >> 11, d = g & (D_INNER - 1);
    const float a = Aneg[d * D_STATE + n];
    const float* dl = delta + (long long)g * SEQLEN;
    const float* ul = u + (long long)g * SEQLEN;
    const float* xb = xdbl + (long long)b * SEQLEN * NPROJ + DT_RANK + n;
    float* yl = y + (long long)g * SEQLEN;

    const float4* dv = (const float4*)dl;
    const float4* uv = (const float4*)ul;

    // prefetch block 0
    float4 pd0 = dv[0], pd1 = dv[1];
    float4 pu0 = uv[0], pu1 = uv[1];
    float pB[8], pC[8];
    #pragma unroll
    for (int i = 0; i < 8; ++i) {
        pB[i] = xb[i * NPROJ];
        pC[i] = xb[i * NPROJ + D_STATE];
    }

    float s = 0.f;
    for (int t0 = 0; t0 < SEQLEN; t0 += 8) {
        // copy current block to locals (consumes the waits)
        float cd[8] = {pd0.x, pd0.y, pd0.z, pd0.w, pd1.x, pd1.y, pd1.z, pd1.w};
        float cu[8] = {pu0.x, pu0.y, pu0.z, pu0.w, pu1.x, pu1.y, pu1.z, pu1.w};
        float cB[8], cC[8];
        #pragma unroll
        for (int i = 0; i < 8; ++i) { cB[i] = pB[i]; cC[i] = pC[i]; }
        // issue next block's loads (independent of s)
        if (t0 + 8 < SEQLEN) {
            const int nb = (t0 >> 2) + 2;
            pd0 = dv[nb]; pd1 = dv[nb + 1];
            pu0 = uv[nb]; pu1 = uv[nb + 1];
            const float* xn = xb + (t0 + 8) * NPROJ;
            #pragma unroll
            for (int i = 0; i < 8; ++i) {
                pB[i] = xn[i * NPROJ];
                pC[i] = xn[i * NPROJ + D_STATE];
            }
        }
        // compute 8 steps from registers
        float yo[8];
        #pragma unroll
        for (int i = 0; i < 8; ++i) {
            float dt = cd[i], ut = cu[i];
            s = __expf(dt * a) * s + (dt * ut) * cB[i];
            float p = s * cC[i];
            p += __shfl_xor(p, 8, 16);
            p += __shfl_xor(p, 4, 16);
            p += __shfl_xor(p, 2, 16);
            p += __shfl_xor(p, 1, 16);
            yo[i] = p;
        }
        if (n == 0) {
            #pragma unroll
            for (int i = 0; i < 8; ++i) yl[t0 + i] = yo[i];
        }
    }
}

// ---------------- S[b,l] = sum_d Dp[d]*u[b,d,l] ----------------
__global__ void ssum_k(const float* __restrict__ u, const float* __restrict__ Dp,
                       float* __restrict__ S)
{
    int li = blockIdx.x * 256 + threadIdx.x;
    int c = blockIdx.y;
    int b = li >> 11, l = li & (SEQLEN - 1);
    const float* up = u + (long long)b * D_INNER * SEQLEN + l;
    float acc = 0.f;
    for (int d = c * 256; d < c * 256 + 256; ++d)
        acc += Dp[d] * up[(long long)d * SEQLEN];
    atomicAdd(&S[li], acc);
}

// ---------------- y=(y+Dp*u)*silu(z), transposed into ycat16[...,:2048] -------
__global__ __launch_bounds__(256) void ytrans_k(const float* __restrict__ ysc,
    const float* __restrict__ u, const float* __restrict__ xz,
    const float* __restrict__ Dp, __bf16* __restrict__ ycat)
{
    __shared__ float tile[32][33];
    const int b = blockIdx.z;
    const int d0 = blockIdx.y * 32, l0 = blockIdx.x * 32;
    const int lx = threadIdx.x, dy = threadIdx.y;
    #pragma unroll
    for (int j = 0; j < 4; ++j) {
        int d = d0 + dy + j * 8;
        long long i  = ((long long)b * D_INNER + d) * SEQLEN + l0 + lx;
        long long iz = ((long long)b * 2 * D_INNER + D_INNER + d) * SEQLEN + l0 + lx;
        tile[dy + j * 8][lx] = (ysc[i] + Dp[d] * u[i]) * silu_f(xz[iz]);
    }
    __syncthreads();
    #pragma unroll
    for (int j = 0; j < 4; ++j) {
        int l = l0 + dy + j * 8;
        ycat[((long long)b * SEQLEN + l) * (2 * D_INNER) + d0 + lx] = (__bf16)tile[lx][dy + j * 8];
    }
}

// ---------------- y_t -> ycat16[...,2048:] ----------------
__global__ __launch_bounds__(256) void yt_k(const float* __restrict__ xdbl,
    const float* __restrict__ Aneg, const float* __restrict__ S, __bf16* __restrict__ ycat)
{
    __shared__ float Cs[16][33];
    __shared__ float An[16][64];
    __shared__ float Sv[32];
    const int b = blockIdx.z;
    const int d0 = blockIdx.y * 64, l0 = blockIdx.x * 32;
    const int tid = threadIdx.x;
    for (int f = tid; f < 512; f += 256) {
        int n = f & 15, l = f >> 4;
        Cs[n][l] = xdbl[((long long)b * SEQLEN + l0 + l) * NPROJ + DT_RANK + D_STATE + n];
    }
    for (int f = tid; f < 1024; f += 256) {
        int n = f & 15, d = f >> 4;
        An[n][d] = Aneg[(d0 + d) * D_STATE + n];
    }
    if (tid < 32) Sv[tid] = S[b * SEQLEN + l0 + tid];
    __syncthreads();
    const int dx = tid & 63, lg = tid >> 6;
    #pragma unroll
    for (int j = 0; j < 8; ++j) {
        int l = lg * 8 + j;
        float acc = Sv[l];
        #pragma unroll
        for (int n = 0; n < 16; ++n) acc += Cs[n][l] * An[n][dx];
        ycat[((long long)b * SEQLEN + l0 + l) * (2 * D_INNER) + D_INNER + d0 + dx] = (__bf16)acc;
    }
}

extern "C" void kernel_launch(void* const* d_in, const int* in_sizes, int n_in,
                              void* d_out, int out_size, void* d_ws, size_t ws_size,
                              hipStream_t stream)
{
    const float* x      = (const float*)d_in[0];
    const float* W_in   = (const float*)d_in[1];
    const float* conv_w = (const float*)d_in[2];
    const float* conv_b = (const float*)d_in[3];
    const float* W_x    = (const float*)d_in[4];
    const float* W_dt   = (const float*)d_in[5];
    const float* b_dt   = (const float*)d_in[6];
    const float* A_log  = (const float*)d_in[7];
    const float* Dp     = (const float*)d_in[8];
    const float* W_out1 = (const float*)d_in[9];
    const float* W_out2 = (const float*)d_in[10];
    float* out = (float*)d_out;
    float* ws  = (float*)d_ws;

    // fp32 region (169.5 MB)
    float* xz   = ws;                    // 16777216
    float* u    = xz   + 16777216;       //  8388608
    float* xdbl = u    + 8388608;        //   393216
    float* dtb  = xdbl + 393216;         //  8388608 (delta)
    float* ysc  = dtb  + 8388608;        //  8388608
    float* Aneg = ysc  + 8388608;        //    32768
    float* S    = Aneg + 32768;          //     4096
    // bf16 tail (50.4 MB)
    __bf16* ycat16 = (__bf16*)(S + 4096);          // 16777216 el
    __bf16* h16    = ycat16 + 16777216;            //  8388608 el
    // overlays (regions dead at time of use)
    __bf16* W_in16  = (__bf16*)u;                  // 4194304 el (before conv writes u)
    __bf16* xb16    = W_in16 + 4194304;            // 4194304 el
    __bf16* Wout116 = (__bf16*)dtb;                // 8388608 el (after scan reads dtb)
    __bf16* Wout216 = Wout116 + 8388608;           // 2097152 el

    hipMemsetAsync(xdbl, 0, 393216 * sizeof(float), stream);
    hipMemsetAsync(S, 0, 4096 * sizeof(float), stream);
    aneg_k<<<128, 256, 0, stream>>>(A_log, Aneg);

    // bf16 conversions for input GEMM
    cvt_bf16_k<<<2048, 256, 0, stream>>>(W_in, W_in16, 524288);
    cvt_bf16_k<<<2048, 256, 0, stream>>>(x, xb16, 524288);

    // xz[b,e,l] = sum_d W_in[e,d] * x[b,l,d]   (M=4096, N=2048, K=1024)
    gemm_bf16_k<0, 0><<<dim3(16, 32, BATCH), 256, 0, stream>>>(
        W_in16, xb16, xz, D_MODEL, D_MODEL, D_MODEL, SEQLEN,
        (long long)SEQLEN * D_MODEL, (long long)4096 * SEQLEN);

    conv_silu_k<<<(BATCH * D_INNER * SEQLEN) / 256, 256, 0, stream>>>(xz, conv_w, conv_b, u);

    xdbl_k<<<dim3(SEQLEN / 64, 4, BATCH), 256, 0, stream>>>(u, W_x, xdbl);

    // dt[b,d,l] = sum_r W_dt[d,r] * x_dbl[b,l,r]   (small K=64, fp32)
    gemm_nt_k<0><<<dim3(SEQLEN / 64, D_INNER / 64, BATCH), 256, 0, stream>>>(
        W_dt, xdbl, dtb, D_INNER, SEQLEN, DT_RANK, DT_RANK, NPROJ, SEQLEN,
        0LL, (long long)SEQLEN * NPROJ, (long long)D_INNER * SEQLEN);

    softplus_k<<<(BATCH * D_INNER * SEQLEN) / 256, 256, 0, stream>>>(dtb, b_dt);

    scan_k<<<(BATCH * D_INNER) / 4, 64, 0, stream>>>(dtb, u, xdbl, Aneg, ysc);

    // weight conversions for output GEMMs (dtb region dead now)
    cvt_bf16_k<<<4096, 256, 0, stream>>>(W_out1, Wout116, 1048576);
    cvt_bf16_k<<<1024, 256, 0, stream>>>(W_out2, Wout216, 262144);

    ssum_k<<<dim3((BATCH * SEQLEN) / 256, 8), 256, 0, stream>>>(u, Dp, S);

    ytrans_k<<<dim3(SEQLEN / 32, D_INNER / 32, BATCH), dim3(32, 8), 0, stream>>>(ysc, u, xz, Dp, ycat16);

    yt_k<<<dim3(SEQLEN / 32, D_INNER / 64, BATCH), 256, 0, stream>>>(xdbl, Aneg, S, ycat16);

    // h = relu(ycat @ W_out1^T) -> bf16   (M=4096, N=2048, K=4096)
    gemm_bf16_k<1, 1><<<dim3(16, 32, 1), 256, 0, stream>>>(
        ycat16, Wout116, h16, 2 * D_INNER, 2 * D_INNER, 2 * D_INNER, D_INNER, 0LL, 0LL);

    // out = h @ W_out2^T   (M=4096, N=1024, K=2048)
    gemm_bf16_k<0, 0><<<dim3(8, 32, 1), 256, 0, stream>>>(
        h16, Wout216, out, D_INNER, D_INNER, D_INNER, D_MODEL, 0LL, 0LL);
}

// Round 8
// 653.147 us; speedup vs baseline: 4.1118x; 1.1325x over previous
//
#include <hip/hip_runtime.h>
#include <hip/hip_bf16.h>
#include <math.h>

#define D_MODEL 1024
#define D_STATE 16
#define D_INNER 2048
#define DT_RANK 64
#define BATCH   2
#define SEQLEN  2048
#define NPROJ   96   // DT_RANK + 2*D_STATE

typedef __attribute__((ext_vector_type(8))) __bf16 bf16x8;
typedef __attribute__((ext_vector_type(4))) float f32x4;

__device__ __forceinline__ float silu_f(float x) { return x / (1.f + __expf(-x)); }

__device__ __forceinline__ void gload_lds16(const void* g, void* l) {
    __builtin_amdgcn_global_load_lds((const __attribute__((address_space(1))) void*)g,
                                     (__attribute__((address_space(3))) void*)l, 16, 0, 0);
}

// ---------------- bf16 MFMA NT GEMM: C[m,n] = sum_k A[m,k]*B[n,k] -------------
// BM=BN=128, BK=32, 256 threads = 4 waves (2x2), 64x64 per wave.
// One mfma_16x16x32 consumes the full BK=32 (lane k-offset = (lane>>4)*8).
// M,N mult of 128, K mult of 32. A un-batched, B/C batched via strides.
template<int RELU, int OUT_BF16>
__global__ __launch_bounds__(256) void gemm_bf16_k(
    const __bf16* __restrict__ A, const __bf16* __restrict__ B, void* __restrict__ Cv,
    int K, int lda, int ldb, int ldc, long long sB, long long sC)
{
    __shared__ alignas(16) __bf16 As[128 * 32];
    __shared__ alignas(16) __bf16 Bs[128 * 32];
    const int bz = blockIdx.z;
    B += (long long)bz * sB;
    const int m0 = blockIdx.y * 128, n0 = blockIdx.x * 128;
    const int tid = threadIdx.x;
    const int lane = tid & 63;
    const int wv = tid >> 6;
    const int wr = wv >> 1, wc = wv & 1;

    f32x4 acc[4][4];
    #pragma unroll
    for (int i = 0; i < 4; ++i)
        #pragma unroll
        for (int j = 0; j < 4; ++j) acc[i][j] = (f32x4){0.f, 0.f, 0.f, 0.f};

    const int ko = (lane >> 4) * 8;           // k-offset within BK=32
    const int fr = lane & 15;                 // fragment row/col within 16

    for (int k0 = 0; k0 < K; k0 += 32) {
        #pragma unroll
        for (int q = 0; q < 2; ++q) {
            int f = tid + q * 256;
            int row = f >> 2, c16 = f & 3;    // 4 x 16B per 32-elem row
            gload_lds16(A + (long long)(m0 + row) * lda + k0 + c16 * 8, As + f * 8);
            gload_lds16(B + (long long)(n0 + row) * ldb + k0 + c16 * 8, Bs + f * 8);
        }
        __syncthreads();
        bf16x8 a[4], b[4];
        #pragma unroll
        for (int i = 0; i < 4; ++i) {
            a[i] = *(const bf16x8*)(As + (wr * 64 + i * 16 + fr) * 32 + ko);
            b[i] = *(const bf16x8*)(Bs + (wc * 64 + i * 16 + fr) * 32 + ko);
        }
        #pragma unroll
        for (int i = 0; i < 4; ++i)
            #pragma unroll
            for (int j = 0; j < 4; ++j)
                acc[i][j] = __builtin_amdgcn_mfma_f32_16x16x32_bf16(a[i], b[j], acc[i][j], 0, 0, 0);
        __syncthreads();
    }

    #pragma unroll
    for (int i = 0; i < 4; ++i) {
        const int row = m0 + wr * 64 + i * 16 + (lane >> 4) * 4;
        #pragma unroll
        for (int j = 0; j < 4; ++j) {
            const int col = n0 + wc * 64 + j * 16 + fr;
            #pragma unroll
            for (int r = 0; r < 4; ++r) {
                float v = acc[i][j][r];
                if (RELU) v = fmaxf(v, 0.f);
                if (OUT_BF16)
                    ((__bf16*)Cv)[(long long)bz * sC + (long long)(row + r) * ldc + col] = (__bf16)v;
                else
                    ((float*)Cv)[(long long)bz * sC + (long long)(row + r) * ldc + col] = v;
            }
        }
    }
}

// ---------------- f32 -> bf16 pack (8 per thread) ----------------
__global__ void cvt_bf16_k(const float* __restrict__ in, __bf16* __restrict__ out, int n8) {
    int i = blockIdx.x * 256 + threadIdx.x;
    if (i >= n8) return;
    const f32x4* p = (const f32x4*)in + (long long)i * 2;
    f32x4 v0 = p[0], v1 = p[1];
    bf16x8 o;
    o[0] = (__bf16)v0[0]; o[1] = (__bf16)v0[1]; o[2] = (__bf16)v0[2]; o[3] = (__bf16)v0[3];
    o[4] = (__bf16)v1[0]; o[5] = (__bf16)v1[1]; o[6] = (__bf16)v1[2]; o[7] = (__bf16)v1[3];
    ((bf16x8*)out)[i] = o;
}

// ---------------- generic fp32 NT GEMM (kept for small dt GEMM) ----------------
template<int RELU>
__global__ __launch_bounds__(256) void gemm_nt_k(
    const float* __restrict__ A, const float* __restrict__ B, float* __restrict__ C,
    int M, int N, int K, int lda, int ldb, int ldc,
    long long sA, long long sB, long long sC)
{
    __shared__ float As[16][68];
    __shared__ float Bs[16][68];
    const int bz = blockIdx.z;
    A += (long long)bz * sA; B += (long long)bz * sB; C += (long long)bz * sC;
    const int m0 = blockIdx.y * 64, n0 = blockIdx.x * 64;
    const int tid = threadIdx.x;
    const int lk = tid & 15, lr = tid >> 4;
    const int tx = tid & 15, ty = tid >> 4;
    float acc[4][4] = {};
    for (int k0 = 0; k0 < K; k0 += 16) {
        #pragma unroll
        for (int q = 0; q < 4; ++q) {
            int i = lr + q * 16;
            As[lk][i] = A[(long long)(m0 + i) * lda + k0 + lk];
            Bs[lk][i] = B[(long long)(n0 + i) * ldb + k0 + lk];
        }
        __syncthreads();
        #pragma unroll
        for (int k = 0; k < 16; ++k) {
            float a[4], b[4];
            #pragma unroll
            for (int j = 0; j < 4; ++j) { a[j] = As[k][ty*4+j]; b[j] = Bs[k][tx*4+j]; }
            #pragma unroll
            for (int i = 0; i < 4; ++i)
                #pragma unroll
                for (int j = 0; j < 4; ++j) acc[i][j] += a[i] * b[j];
        }
        __syncthreads();
    }
    #pragma unroll
    for (int i = 0; i < 4; ++i)
        #pragma unroll
        for (int j = 0; j < 4; ++j) {
            float v = acc[i][j];
            if (RELU) v = fmaxf(v, 0.f);
            C[(long long)(m0 + ty*4 + i) * ldc + n0 + tx*4 + j] = v;
        }
}

// ---------------- Aneg = -exp(A_log) ----------------
__global__ void aneg_k(const float* __restrict__ A_log, float* __restrict__ Aneg) {
    int i = blockIdx.x * 256 + threadIdx.x;
    if (i < D_INNER * D_STATE) Aneg[i] = -expf(A_log[i]);
}

// ---------------- depthwise causal conv(4) + bias + SiLU ----------------
__global__ void conv_silu_k(const float* __restrict__ xz, const float* __restrict__ cw,
                            const float* __restrict__ cb, float* __restrict__ u)
{
    int idx = blockIdx.x * 256 + threadIdx.x;
    int l = idx & (SEQLEN - 1);
    int d = (idx >> 11) & (D_INNER - 1);
    int b = idx >> 22;
    const float* xi = xz + ((long long)b * 2 * D_INNER + d) * SEQLEN;
    float acc = cb[d];
    #pragma unroll
    for (int k = 0; k < 4; ++k) {
        int t = l + k - 3;
        if (t >= 0) acc += xi[t] * cw[d * 4 + k];
    }
    u[idx] = silu_f(acc);
}

// ---------------- x_dbl[b,l,e] = sum_d u[b,d,l] * W_x[e,d] ----------------
__global__ __launch_bounds__(256) void xdbl_k(const float* __restrict__ u,
    const float* __restrict__ Wx, float* __restrict__ xdbl)
{
    __shared__ float Us[32][65];
    __shared__ float Ws[32][96];
    const int b = blockIdx.z;
    const int l0 = blockIdx.x * 64;
    const int k0base = blockIdx.y * 512;
    const int tid = threadIdx.x;
    const int lx = tid & 63, eg = tid >> 6;
    float acc[24] = {};
    for (int kc = 0; kc < 16; ++kc) {
        int k0 = k0base + kc * 32;
        #pragma unroll
        for (int q = 0; q < 8; ++q) {
            int f = tid + q * 256;
            int kk = f >> 6, l = f & 63;
            Us[kk][l] = u[((long long)b * D_INNER + k0 + kk) * SEQLEN + l0 + l];
        }
        #pragma unroll
        for (int q = 0; q < 12; ++q) {
            int f = tid + q * 256;
            int kk = f & 31, e = f >> 5;
            Ws[kk][e] = Wx[(long long)e * D_INNER + k0 + kk];
        }
        __syncthreads();
        #pragma unroll
        for (int kk = 0; kk < 32; ++kk) {
            float a = Us[kk][lx];
            #pragma unroll
            for (int j = 0; j < 24; ++j) acc[j] += a * Ws[kk][eg * 24 + j];
        }
        __syncthreads();
    }
    #pragma unroll
    for (int j = 0; j < 24; ++j)
        atomicAdd(&xdbl[((long long)b * SEQLEN + l0 + lx) * NPROJ + eg * 24 + j], acc[j]);
}

// ---------------- delta = softplus(dt + b_dt) in place ----------------
__global__ void softplus_k(float* __restrict__ dtb, const float* __restrict__ b_dt) {
    int idx = blockIdx.x * 256 + threadIdx.x;
    int d = (idx >> 11) & (D_INNER - 1);
    float v = dtb[idx] + b_dt[d];
    dtb[idx] = fmaxf(v, 0.f) + log1pf(expf(-fabsf(v)));
}

// ---------------- selective scan: 16 lanes per (b,d) chain, 16-step blocks ----
// Per block: (1) prefetched operands -> dA/wB off the critical path (the
// recurrence is then 16 dependent v_fma), (2) p = s*C written to LDS,
// (3) one batched LDS transpose-reduce (lane t sums 16 n-values) replaces the
// 4-deep serial __shfl_xor chains whose exposed LDS latency dominated R7.
__global__ __launch_bounds__(64, 1) void scan_k(const float* __restrict__ delta,
    const float* __restrict__ u, const float* __restrict__ xdbl,
    const float* __restrict__ Aneg, float* __restrict__ y)
{
    __shared__ float lp[4][16][17];        // [chain][n][t] padded: conflict-free
    const int q = threadIdx.x >> 4;        // chain slot within wave
    const int n = threadIdx.x & 15;
    const int g = blockIdx.x * 4 + q;      // chain id = b*D_INNER + d
    const int b = g >> 11, d = g & (D_INNER - 1);
    const float a = Aneg[d * D_STATE + n];
    const float4* dv = (const float4*)(delta + (long long)g * SEQLEN);
    const float4* uv = (const float4*)(u + (long long)g * SEQLEN);
    const float* xb = xdbl + (long long)b * SEQLEN * NPROJ + DT_RANK + n;
    float* yl = y + (long long)g * SEQLEN;

    // prefetch block 0
    float4 pd[4], pu[4];
    float pB[16], pC[16];
    #pragma unroll
    for (int i = 0; i < 4; ++i) { pd[i] = dv[i]; pu[i] = uv[i]; }
    #pragma unroll
    for (int i = 0; i < 16; ++i) { pB[i] = xb[i * NPROJ]; pC[i] = xb[i * NPROJ + D_STATE]; }

    float s = 0.f;
    for (int t0 = 0; t0 < SEQLEN; t0 += 16) {
        // current block to locals (consumes the waits)
        float cd[16], cu[16], cB[16], cC[16];
        #pragma unroll
        for (int i = 0; i < 4; ++i) {
            cd[4*i] = pd[i].x; cd[4*i+1] = pd[i].y; cd[4*i+2] = pd[i].z; cd[4*i+3] = pd[i].w;
            cu[4*i] = pu[i].x; cu[4*i+1] = pu[i].y; cu[4*i+2] = pu[i].z; cu[4*i+3] = pu[i].w;
        }
        #pragma unroll
        for (int i = 0; i < 16; ++i) { cB[i] = pB[i]; cC[i] = pC[i]; }
        // issue next block's loads (independent of s)
        if (t0 + 16 < SEQLEN) {
            const int nb = (t0 >> 2) + 4;
            #pragma unroll
            for (int i = 0; i < 4; ++i) { pd[i] = dv[nb + i]; pu[i] = uv[nb + i]; }
            const float* xn = xb + (t0 + 16) * NPROJ;
            #pragma unroll
            for (int i = 0; i < 16; ++i) { pB[i] = xn[i * NPROJ]; pC[i] = xn[i * NPROJ + D_STATE]; }
        }
        // off-critical-path: dA, wB
        float dA[16], wB[16];
        #pragma unroll
        for (int i = 0; i < 16; ++i) {
            dA[i] = __expf(cd[i] * a);
            wB[i] = cd[i] * cu[i] * cB[i];
        }
        // serial recurrence: 16 dependent FMAs; p scattered to LDS off-path
        #pragma unroll
        for (int i = 0; i < 16; ++i) {
            s = dA[i] * s + wB[i];
            lp[q][n][i] = s * cC[i];
        }
        __syncthreads();
        // transpose-reduce: lane n sums column t=n over the 16 states
        float v[16];
        #pragma unroll
        for (int j = 0; j < 16; ++j) v[j] = lp[q][j][n];
        float acc = 0.f;
        #pragma unroll
        for (int j = 0; j < 16; ++j) acc += v[j];
        yl[t0 + n] = acc;
        __syncthreads();
    }
}

// ---------------- S[b,l] = sum_d Dp[d]*u[b,d,l] ----------------
__global__ void ssum_k(const float* __restrict__ u, const float* __restrict__ Dp,
                       float* __restrict__ S)
{
    int li = blockIdx.x * 256 + threadIdx.x;
    int c = blockIdx.y;
    int b = li >> 11, l = li & (SEQLEN - 1);
    const float* up = u + (long long)b * D_INNER * SEQLEN + l;
    float acc = 0.f;
    for (int d = c * 256; d < c * 256 + 256; ++d)
        acc += Dp[d] * up[(long long)d * SEQLEN];
    atomicAdd(&S[li], acc);
}

// ---------------- y=(y+Dp*u)*silu(z), transposed into ycat16[...,:2048] -------
__global__ __launch_bounds__(256) void ytrans_k(const float* __restrict__ ysc,
    const float* __restrict__ u, const float* __restrict__ xz,
    const float* __restrict__ Dp, __bf16* __restrict__ ycat)
{
    __shared__ float tile[32][33];
    const int b = blockIdx.z;
    const int d0 = blockIdx.y * 32, l0 = blockIdx.x * 32;
    const int lx = threadIdx.x, dy = threadIdx.y;
    #pragma unroll
    for (int j = 0; j < 4; ++j) {
        int d = d0 + dy + j * 8;
        long long i  = ((long long)b * D_INNER + d) * SEQLEN + l0 + lx;
        long long iz = ((long long)b * 2 * D_INNER + D_INNER + d) * SEQLEN + l0 + lx;
        tile[dy + j * 8][lx] = (ysc[i] + Dp[d] * u[i]) * silu_f(xz[iz]);
    }
    __syncthreads();
    #pragma unroll
    for (int j = 0; j < 4; ++j) {
        int l = l0 + dy + j * 8;
        ycat[((long long)b * SEQLEN + l) * (2 * D_INNER) + d0 + lx] = (__bf16)tile[lx][dy + j * 8];
    }
}

// ---------------- y_t -> ycat16[...,2048:] ----------------
__global__ __launch_bounds__(256) void yt_k(const float* __restrict__ xdbl,
    const float* __restrict__ Aneg, const float* __restrict__ S, __bf16* __restrict__ ycat)
{
    __shared__ float Cs[16][33];
    __shared__ float An[16][64];
    __shared__ float Sv[32];
    const int b = blockIdx.z;
    const int d0 = blockIdx.y * 64, l0 = blockIdx.x * 32;
    const int tid = threadIdx.x;
    for (int f = tid; f < 512; f += 256) {
        int n = f & 15, l = f >> 4;
        Cs[n][l] = xdbl[((long long)b * SEQLEN + l0 + l) * NPROJ + DT_RANK + D_STATE + n];
    }
    for (int f = tid; f < 1024; f += 256) {
        int n = f & 15, d = f >> 4;
        An[n][d] = Aneg[(d0 + d) * D_STATE + n];
    }
    if (tid < 32) Sv[tid] = S[b * SEQLEN + l0 + tid];
    __syncthreads();
    const int dx = tid & 63, lg = tid >> 6;
    #pragma unroll
    for (int j = 0; j < 8; ++j) {
        int l = lg * 8 + j;
        float acc = Sv[l];
        #pragma unroll
        for (int n = 0; n < 16; ++n) acc += Cs[n][l] * An[n][dx];
        ycat[((long long)b * SEQLEN + l0 + l) * (2 * D_INNER) + D_INNER + d0 + dx] = (__bf16)acc;
    }
}

extern "C" void kernel_launch(void* const* d_in, const int* in_sizes, int n_in,
                              void* d_out, int out_size, void* d_ws, size_t ws_size,
                              hipStream_t stream)
{
    const float* x      = (const float*)d_in[0];
    const float* W_in   = (const float*)d_in[1];
    const float* conv_w = (const float*)d_in[2];
    const float* conv_b = (const float*)d_in[3];
    const float* W_x    = (const float*)d_in[4];
    const float* W_dt   = (const float*)d_in[5];
    const float* b_dt   = (const float*)d_in[6];
    const float* A_log  = (const float*)d_in[7];
    const float* Dp     = (const float*)d_in[8];
    const float* W_out1 = (const float*)d_in[9];
    const float* W_out2 = (const float*)d_in[10];
    float* out = (float*)d_out;
    float* ws  = (float*)d_ws;

    // fp32 region (169.5 MB)
    float* xz   = ws;                    // 16777216
    float* u    = xz   + 16777216;       //  8388608
    float* xdbl = u    + 8388608;        //   393216
    float* dtb  = xdbl + 393216;         //  8388608 (delta)
    float* ysc  = dtb  + 8388608;        //  8388608
    float* Aneg = ysc  + 8388608;        //    32768
    float* S    = Aneg + 32768;          //     4096
    // bf16 tail (50.4 MB)
    __bf16* ycat16 = (__bf16*)(S + 4096);          // 16777216 el
    __bf16* h16    = ycat16 + 16777216;            //  8388608 el
    // overlays (regions dead at time of use)
    __bf16* W_in16  = (__bf16*)u;                  // 4194304 el (before conv writes u)
    __bf16* xb16    = W_in16 + 4194304;            // 4194304 el
    __bf16* Wout116 = (__bf16*)dtb;                // 8388608 el (after scan reads dtb)
    __bf16* Wout216 = Wout116 + 8388608;           // 2097152 el

    hipMemsetAsync(xdbl, 0, 393216 * sizeof(float), stream);
    hipMemsetAsync(S, 0, 4096 * sizeof(float), stream);
    aneg_k<<<128, 256, 0, stream>>>(A_log, Aneg);

    // bf16 conversions for input GEMM
    cvt_bf16_k<<<2048, 256, 0, stream>>>(W_in, W_in16, 524288);
    cvt_bf16_k<<<2048, 256, 0, stream>>>(x, xb16, 524288);

    // xz[b,e,l] = sum_d W_in[e,d] * x[b,l,d]   (M=4096, N=2048, K=1024)
    gemm_bf16_k<0, 0><<<dim3(16, 32, BATCH), 256, 0, stream>>>(
        W_in16, xb16, xz, D_MODEL, D_MODEL, D_MODEL, SEQLEN,
        (long long)SEQLEN * D_MODEL, (long long)4096 * SEQLEN);

    conv_silu_k<<<(BATCH * D_INNER * SEQLEN) / 256, 256, 0, stream>>>(xz, conv_w, conv_b, u);

    xdbl_k<<<dim3(SEQLEN / 64, 4, BATCH), 256, 0, stream>>>(u, W_x, xdbl);

    // dt[b,d,l] = sum_r W_dt[d,r] * x_dbl[b,l,r]   (small K=64, fp32)
    gemm_nt_k<0><<<dim3(SEQLEN / 64, D_INNER / 64, BATCH), 256, 0, stream>>>(
        W_dt, xdbl, dtb, D_INNER, SEQLEN, DT_RANK, DT_RANK, NPROJ, SEQLEN,
        0LL, (long long)SEQLEN * NPROJ, (long long)D_INNER * SEQLEN);

    softplus_k<<<(BATCH * D_INNER * SEQLEN) / 256, 256, 0, stream>>>(dtb, b_dt);

    scan_k<<<(BATCH * D_INNER) / 4, 64, 0, stream>>>(dtb, u, xdbl, Aneg, ysc);

    // weight conversions for output GEMMs (dtb region dead now)
    cvt_bf16_k<<<4096, 256, 0, stream>>>(W_out1, Wout116, 1048576);
    cvt_bf16_k<<<1024, 256, 0, stream>>>(W_out2, Wout216, 262144);

    ssum_k<<<dim3((BATCH * SEQLEN) / 256, 8), 256, 0, stream>>>(u, Dp, S);

    ytrans_k<<<dim3(SEQLEN / 32, D_INNER / 32, BATCH), dim3(32, 8), 0, stream>>>(ysc, u, xz, Dp, ycat16);

    yt_k<<<dim3(SEQLEN / 32, D_INNER / 64, BATCH), 256, 0, stream>>>(xdbl, Aneg, S, ycat16);

    // h = relu(ycat @ W_out1^T) -> bf16   (M=4096, N=2048, K=4096)
    gemm_bf16_k<1, 1><<<dim3(16, 32, 1), 256, 0, stream>>>(
        ycat16, Wout116, h16, 2 * D_INNER, 2 * D_INNER, 2 * D_INNER, D_INNER, 0LL, 0LL);

    // out = h @ W_out2^T   (M=4096, N=1024, K=2048)
    gemm_bf16_k<0, 0><<<dim3(8, 32, 1), 256, 0, stream>>>(
        h16, Wout216, out, D_INNER, D_INNER, D_INNER, D_MODEL, 0LL, 0LL);
}